// Round 7
// baseline (805.838 us; speedup 1.0000x reference)
//
#include <hip/hip_runtime.h>
#include <stdint.h>

#define BB 32
#define CIN 128
#define COUT 256
#define HH 64
#define WW 64
#define TOPK 64
#define NS_F (8.0f/255.0f)
#define GAPF 2.5e-4f      // ambiguity band; pipeline error vs fp64-exact ~1e-5 tail -> >=8x margin
#define NS_D (8.0/255.0)
#define EPI_STRIDE 258    // floats per epilogue pos-row (256 ch + pad)
#define LIST_CAP 65536
#define XT_BYTES 33792    // one image's [66][2][128] bf16 tile

typedef __bf16 bf16x8 __attribute__((ext_vector_type(8)));
typedef float f32x4 __attribute__((ext_vector_type(4)));

__device__ __forceinline__ unsigned short bf_bits(float v) {
    __bf16 b = (__bf16)v;
    return __builtin_bit_cast(unsigned short, b);
}
__device__ __forceinline__ float bf_round(float v) { return (float)(__bf16)v; }

// swizzled byte offset into xT LDS tile: [ww 0..65][s 0..1][ci 0..127] bf16, row=512B
__device__ __forceinline__ int xoff(int ww, int s, int ci) {
    int byte = (ww << 9) + (s << 8) + (ci << 1);
    return byte ^ ((ww & 7) << 4);
}

// ---- 32-bit monotone float keys
__device__ __forceinline__ uint32_t skey32(float v) {
    uint32_t b = __float_as_uint(v);
    return (b & 0x80000000u) ? ~b : (b | 0x80000000u);
}
__device__ __forceinline__ float unskey32(uint32_t k) {
    uint32_t b = (k & 0x80000000u) ? (k & 0x7FFFFFFFu) : ~k;
    return __uint_as_float(b);
}

// ---- 64-bit keys (fixup kernel, exact fp64 path)
__device__ __forceinline__ uint64_t sortkey(double v) {
    uint64_t b = (uint64_t)__double_as_longlong(v);
    return (b & 0x8000000000000000ULL) ? ~b : (b | 0x8000000000000000ULL);
}
__device__ __forceinline__ double unsortkey(uint64_t k) {
    uint64_t b = (k & 0x8000000000000000ULL) ? (k & 0x7FFFFFFFFFFFFFFFULL) : ~k;
    return __longlong_as_double((long long)b);
}

// per-wave exact select over 256 u32 keys (4/lane): 64th/65th largest + exact count at prefix.
// bestcnt != 64  <=>  fp32 keys cannot uniquely separate rank 64/65 (ties) -> caller must flag.
__device__ __forceinline__ void select64_u32(const uint32_t u[4], uint32_t& k64, uint32_t& k65, int& bestcnt) {
    uint32_t prefix = 0;
    bestcnt = 256;
    for (int bit = 31; bit >= 0; --bit) {
        uint32_t cand = prefix | (1u << bit);
        int cnt = __popcll(__ballot(u[0] >= cand)) + __popcll(__ballot(u[1] >= cand))
                + __popcll(__ballot(u[2] >= cand)) + __popcll(__ballot(u[3] >= cand));
        if (cnt >= TOPK) {
            prefix = cand;
            bestcnt = cnt;
            if (cnt == TOPK) break;
        }
    }
    uint32_t mn = 0xFFFFFFFFu, mx = 0u;
#pragma unroll
    for (int j = 0; j < 4; ++j) {
        if (u[j] >= prefix) { if (u[j] < mn) mn = u[j]; }
        else                { if (u[j] > mx) mx = u[j]; }
    }
    for (int m = 1; m < 64; m <<= 1) {
        uint32_t a = (uint32_t)__shfl_xor((int)mn, m, 64);
        if (a < mn) mn = a;
        uint32_t b = (uint32_t)__shfl_xor((int)mx, m, 64);
        if (b > mx) mx = b;
    }
    k64 = mn; k65 = mx;
}

// per-wave exact select over 256 u64 keys (fixup path)
__device__ __forceinline__ void select64(const uint64_t u[4], uint64_t& k64, uint64_t& k65) {
    uint64_t prefix = 0;
    for (int bit = 63; bit >= 0; --bit) {
        uint64_t cand = prefix | (1ULL << bit);
        int cnt = __popcll(__ballot(u[0] >= cand)) + __popcll(__ballot(u[1] >= cand))
                + __popcll(__ballot(u[2] >= cand)) + __popcll(__ballot(u[3] >= cand));
        if (cnt >= TOPK) {
            prefix = cand;
            if (cnt == TOPK) break;
        }
    }
    uint64_t mn = ~0ULL, mx = 0ULL;
#pragma unroll
    for (int j = 0; j < 4; ++j) {
        if (u[j] >= prefix) { if (u[j] < mn) mn = u[j]; }
        else                { if (u[j] > mx) mx = u[j]; }
    }
    for (int m = 1; m < 64; m <<= 1) {
        uint64_t a = (uint64_t)__shfl_xor((unsigned long long)mn, m, 64);
        if (a < mn) mn = a;
        uint64_t b = (uint64_t)__shfl_xor((unsigned long long)mx, m, 64);
        if (b > mx) mx = b;
    }
    k64 = mn; k65 = mx;
}

// ---------------- prep (merged): absw (fp64) + wT (fp32, fixup) + wB (bf16 hi/lo) + counter reset
__global__ __launch_bounds__(128) void prep_all(const float* __restrict__ w,
                                                double* __restrict__ absw,
                                                float* __restrict__ wT,
                                                unsigned short* __restrict__ wB,
                                                int* __restrict__ counter) {
    const int c = blockIdx.x;      // 0..255
    const int ci = threadIdx.x;    // 0..127
    if (c == 0 && ci == 0) counter[0] = 0;
    double s = 0.0;
#pragma unroll
    for (int r = 0; r < 9; ++r) {
        float v = w[((size_t)c * CIN + ci) * 9 + r];
        s += fabs((double)v);
        float hf = bf_round(v);
        wT[((size_t)(r * CIN) + ci) * COUT + c] = v;
        wB[((size_t)r * COUT + c) * CIN + ci] = bf_bits(v);                 // split 0 (hi)
        wB[((size_t)(9 + r) * COUT + c) * CIN + ci] = bf_bits(v - hf);      // split 1 (lo)
    }
    __shared__ double red[2];
    for (int m = 32; m; m >>= 1) s += __shfl_xor(s, m, 64);
    if ((ci & 63) == 0) red[ci >> 6] = s;
    __syncthreads();
    if (ci == 0) absw[c] = red[0] + red[1];
}

// ---------------- fused: bf16-split MFMA conv + fp32 epilogue + ambiguity flagging
// (R5 structure: compiler-scheduled K-loop, 2 images/block, 2x32-position epilogue passes)
__global__ __launch_bounds__(256, 2) void fused_kernel(
    const float* __restrict__ x,
    const float* __restrict__ relu_bias,
    const float* __restrict__ noise,
    const double* __restrict__ absw,
    const unsigned short* __restrict__ wB,   // bf16 bits [s][kh][kw][c][ci]
    float* __restrict__ out,
    int* __restrict__ counter,
    int* __restrict__ list) {

    __shared__ alignas(16) union {
        unsigned short xT[2 * 66 * 256];   // 2 images x [ww][s][ci], swizzled; 67584 B
        float o[32 * EPI_STRIDE];          // 33024 B  (32 positions per pass)
    } U;
    __shared__ float lds_absw[COUT];
    __shared__ float lds_bias[COUT];
    __shared__ uint32_t thrk[32];

    const int tid = threadIdx.x;
    const int lane = tid & 63;
    const int wv = tid >> 6;          // channel quarter: c in [wv*64, wv*64+64)

    // XCD-aware bijective swizzle: 1024 blocks, 8 XCDs
    const int bid = ((int)(blockIdx.x & 7) << 7) + ((int)blockIdx.x >> 3);
    const int b0 = (bid >> 6) * 2;    // image pair
    const int h = bid & 63;

    lds_absw[tid] = (float)absw[tid];
    lds_bias[tid] = relu_bias[tid];

    const int kgrp8 = (lane >> 4) << 3;

    f32x4 acc[2][4][4];   // [img][m-tile 16pos][n-tile 16ch]
#pragma unroll
    for (int g = 0; g < 2; ++g)
#pragma unroll
        for (int i = 0; i < 4; ++i)
#pragma unroll
            for (int j = 0; j < 4; ++j) {
                acc[g][i][j][0] = 0.f; acc[g][i][j][1] = 0.f;
                acc[g][i][j][2] = 0.f; acc[g][i][j][3] = 0.f;
            }

    char* xb = (char*)U.xT;

    // halo columns ww=0 and ww=65 (zeros), both splits, both images
    if (tid < 128) {
        int img = tid >> 6;
        int t = tid & 63;
        int wwz = (t & 32) ? 65 : 0;
        int sz = (t >> 4) & 1;
        int c0z = (t & 15) << 3;
        bf16x8 z;
#pragma unroll
        for (int j = 0; j < 8; ++j) z[j] = (__bf16)0.f;
        *(bf16x8*)(xb + img * XT_BYTES + xoff(wwz, sz, c0z)) = z;
    }

    // B pointer lane offset: channel = wv*64 + (lane&15) (+16 per nt), k = (lane>>4)*8 within ci0 chunk
    const int laneB = ((lane & 15) << 7) + ((lane >> 4) << 3) + (wv << 13);

    for (int kh = 0; kh < 3; ++kh) {
        const int r = h + kh - 1;
        if (r < 0 || r >= HH) continue;   // uniform per block
        __syncthreads();                  // previous kh readers done (also covers halo init)
        // ---- stage both images' x row-slab -> xT (bf16 hi/lo, transposed, swizzled)
        {
            const int w = lane;           // ww = w+1
#pragma unroll
            for (int img = 0; img < 2; ++img) {
                const float* xr = x + (((size_t)(b0 + img) * CIN) * HH + (size_t)r) * WW;
                char* xbi = xb + img * XT_BYTES;
#pragma unroll
                for (int rep = 0; rep < 4; ++rep) {
                    const int c0 = rep * 32 + wv * 8;
                    const float* px = xr + (size_t)c0 * (HH * WW) + w;
                    bf16x8 hv, lv;
#pragma unroll
                    for (int j = 0; j < 8; ++j) {
                        float v = px[j * (HH * WW)];
                        float hf = bf_round(v);
                        hv[j] = (__bf16)v;
                        lv[j] = (__bf16)(v - hf);
                    }
                    *(bf16x8*)(xbi + xoff(w + 1, 0, c0)) = hv;
                    *(bf16x8*)(xbi + xoff(w + 1, 1, c0)) = lv;
                }
            }
        }
        __syncthreads();
        // ---- MFMA K-loop (compiler-scheduled; 3-kw window gives load-hoisting room)
#pragma unroll 1
        for (int ci0 = 0; ci0 < CIN; ci0 += 32) {
#pragma unroll
            for (int kw = 0; kw < 3; ++kw) {
                const unsigned short* wp0 = wB + (size_t)(kh * 3 + kw) * 32768 + ci0 + laneB;
                const unsigned short* wp1 = wp0 + (size_t)9 * 32768;
                bf16x8 bh[4], bl[4];
#pragma unroll
                for (int nt = 0; nt < 4; ++nt) {
                    bh[nt] = *(const bf16x8*)(wp0 + nt * 2048);
                    bl[nt] = *(const bf16x8*)(wp1 + nt * 2048);
                }
                bf16x8 ah[2][4], al[2][4];
#pragma unroll
                for (int img = 0; img < 2; ++img)
#pragma unroll
                    for (int mt = 0; mt < 4; ++mt) {
                        const int ww = (mt << 4) + (lane & 15) + kw;
                        ah[img][mt] = *(const bf16x8*)(xb + img * XT_BYTES + xoff(ww, 0, ci0 + kgrp8));
                        al[img][mt] = *(const bf16x8*)(xb + img * XT_BYTES + xoff(ww, 1, ci0 + kgrp8));
                    }
#pragma unroll
                for (int img = 0; img < 2; ++img)
#pragma unroll
                    for (int nt = 0; nt < 4; ++nt) {
#pragma unroll
                        for (int mt = 0; mt < 4; ++mt)
                            acc[img][mt][nt] = __builtin_amdgcn_mfma_f32_16x16x32_bf16(ah[img][mt], bh[nt], acc[img][mt][nt], 0, 0, 0);
#pragma unroll
                        for (int mt = 0; mt < 4; ++mt)
                            acc[img][mt][nt] = __builtin_amdgcn_mfma_f32_16x16x32_bf16(al[img][mt], bh[nt], acc[img][mt][nt], 0, 0, 0);
#pragma unroll
                        for (int mt = 0; mt < 4; ++mt)
                            acc[img][mt][nt] = __builtin_amdgcn_mfma_f32_16x16x32_bf16(ah[img][mt], bl[nt], acc[img][mt][nt], 0, 0, 0);
                    }
            }
        }
    }

    // ---------- epilogue: per image, two 32-position passes, all fp32
#pragma unroll
    for (int img = 0; img < 2; ++img) {
        const int b = b0 + img;
#pragma unroll
        for (int q = 0; q < 2; ++q) {
            __syncthreads();
            // phase 1: scatter acc (m-tiles 2q, 2q+1) -> U.o[pos_local][ch]
            // D-frag layout (m89-verified): ch = lane&15 (+tile), pos = (lane>>4)*4 + reg
            {
                const int pl0 = (lane >> 4) << 2;
                const int cb = (wv << 6) + (lane & 15);
#pragma unroll
                for (int half = 0; half < 2; ++half) {
                    const int mt = q * 2 + half;
#pragma unroll
                    for (int nt = 0; nt < 4; ++nt)
#pragma unroll
                        for (int rr = 0; rr < 4; ++rr)
                            U.o[(half * 16 + pl0 + rr) * EPI_STRIDE + cb + nt * 16] = acc[img][mt][nt][rr];
                }
            }
            __syncthreads();
            // phase 2: add noise (fp32)
            {
                int wl = tid & 31;
                int cg = tid >> 5;            // 0..7
                int wg = q * 32 + wl;
#pragma unroll 4
                for (int it = 0; it < 32; ++it) {
                    int c = cg + 8 * it;
                    float u = noise[((size_t)(b * COUT + c) * HH + h) * WW + wg];
                    U.o[wl * EPI_STRIDE + c] += lds_absw[c] * NS_F * (2.f * u - 1.f);
                }
            }
            __syncthreads();
            // phase 3: exact 64th/65th per position (u32 keys); flag ambiguous pixels
            {
#pragma unroll 1
                for (int pp = 0; pp < 8; ++pp) {
                    int pl = wv * 8 + pp;
                    uint32_t u[4];
#pragma unroll
                    for (int j = 0; j < 4; ++j)
                        u[j] = skey32(U.o[pl * EPI_STRIDE + lane + 64 * j]);
                    uint32_t k64, k65; int bcnt;
                    select64_u32(u, k64, k65, bcnt);
                    if (lane == 0) {
                        thrk[pl] = k64;
                        float t64 = unskey32(k64), t65 = unskey32(k65);
                        if (bcnt != 64 || t64 - t65 < GAPF) {
                            int idx = atomicAdd(counter, 1);
                            if (idx < LIST_CAP) list[idx] = (b << 12) | (h << 6) | (q * 32 + pl);
                        }
                    }
                }
            }
            __syncthreads();
            // phase 4: threshold in key space, +bias, relu, store
            {
                int wl = tid & 31;
                int cg = tid >> 5;
                int wg = q * 32 + wl;
                uint32_t tk = thrk[wl];
#pragma unroll 4
                for (int it = 0; it < 32; ++it) {
                    int c = cg + 8 * it;
                    float v = U.o[wl * EPI_STRIDE + c];
                    float o = (skey32(v) >= tk ? v : 0.f) + lds_bias[c];
                    out[((size_t)(b * COUT + c) * HH + h) * WW + wg] = fmaxf(o, 0.f);
                }
            }
        }
    }
}

// ---------------- fixup: exact fp64 recompute of flagged pixels, 8 per block-iteration
// x patches staged as fp32 in LDS (exact: inputs are fp32); math in fp64.
__global__ __launch_bounds__(256, 2) void fixup_kernel(
    const float* __restrict__ x,
    const float* __restrict__ wT,       // [(kh*3+kw)*128+ci][c]
    const float* __restrict__ relu_bias,
    const float* __restrict__ noise,
    const double* __restrict__ absw,
    float* __restrict__ out,
    const int* __restrict__ counter,
    const int* __restrict__ list) {

    __shared__ float xs[8][CIN * 9];      // 36864 B
    __shared__ uint64_t keys[8][COUT];    // 16384 B

    int n = counter[0];
    if (n > LIST_CAP) n = LIST_CAP;

    for (int base = blockIdx.x * 8; base < n; base += gridDim.x * 8) {
        const int np = min(8, n - base);
        __syncthreads();
        for (int q = 0; q < np; ++q) {
            int pix = list[base + q];
            int bb = pix >> 12, hh = (pix >> 6) & 63, ww = pix & 63;
            for (int t = threadIdx.x; t < CIN * 9; t += 256) {
                int r = t >> 7, ci = t & 127;
                int kh = r / 3, kw = r % 3;
                int hr = hh + kh - 1, wr = ww + kw - 1;
                xs[q][t] = (hr >= 0 && hr < HH && wr >= 0 && wr < WW)
                    ? x[(((size_t)(bb * CIN + ci) * HH + hr) * WW) + wr] : 0.0f;
            }
        }
        __syncthreads();
        const int c = threadIdx.x;
        double s[8] = {0.0, 0.0, 0.0, 0.0, 0.0, 0.0, 0.0, 0.0};
#pragma unroll 2
        for (int row = 0; row < CIN * 9; ++row) {
            double wv = (double)wT[(size_t)row * COUT + c];
#pragma unroll
            for (int q = 0; q < 8; ++q)
                s[q] = fma(wv, (double)xs[q][row], s[q]);   // row uniform -> LDS broadcast
        }
#pragma unroll 1
        for (int q = 0; q < np; ++q) {
            int pix = list[base + q];
            int bb = pix >> 12, hh = (pix >> 6) & 63, ww = pix & 63;
            double u = (double)noise[(((size_t)(bb * COUT + c) * HH + hh) * WW) + ww];
            s[q] += absw[c] * NS_D * (2.0 * u - 1.0);
            keys[q][c] = sortkey(s[q]);
        }
        __syncthreads();
#pragma unroll 1
        for (int q = 0; q < np; ++q) {
            uint64_t uu[4];
            int lane = threadIdx.x & 63;
#pragma unroll
            for (int j = 0; j < 4; ++j) uu[j] = keys[q][lane + 64 * j];
            uint64_t k64, k65;
            select64(uu, k64, k65);
            double t64 = unsortkey(k64);
            int pix = list[base + q];
            int bb = pix >> 12, hh = (pix >> 6) & 63, ww = pix & 63;
            double o = (s[q] >= t64 ? s[q] : 0.0) + (double)relu_bias[c];
            out[(((size_t)(bb * COUT + c) * HH + hh) * WW) + ww] = (float)fmax(o, 0.0);
        }
    }
}

extern "C" void kernel_launch(void* const* d_in, const int* in_sizes, int n_in,
                              void* d_out, int out_size, void* d_ws, size_t ws_size,
                              hipStream_t stream) {
    const float* x         = (const float*)d_in[0];
    const float* weight    = (const float*)d_in[1];
    const float* relu_bias = (const float*)d_in[2];
    const float* noise_u   = (const float*)d_in[3];
    float* out = (float*)d_out;

    char* ws = (char*)d_ws;
    double* absw          = (double*)ws;                                   // 2 KB
    float*  wT            = (float*)(ws + 2048);                           // 1,179,648 B
    int*    cnt           = (int*)(ws + 2048 + 1179648);                   // 16 B slot
    int*    list          = (int*)(ws + 2048 + 1179648 + 16);              // 256 KB
    unsigned short* wBq   = (unsigned short*)(ws + 2048 + 1179648 + 16 + 262144); // 1,179,648 B

    prep_all<<<COUT, 128, 0, stream>>>(weight, absw, wT, wBq, cnt);
    fused_kernel<<<(BB / 2) * HH, 256, 0, stream>>>(x, relu_bias, noise_u, absw, wBq, out, cnt, list);
    fixup_kernel<<<1024, 256, 0, stream>>>(x, wT, relu_bias, noise_u, absw, out, cnt, list);
}

// Round 8
// 636.461 us; speedup vs baseline: 1.2661x; 1.2661x over previous
//
#include <hip/hip_runtime.h>
#include <stdint.h>

#define BB 32
#define CIN 128
#define COUT 256
#define HH 64
#define WW 64
#define TOPK 64
#define NS_F (8.0f/255.0f)
#define GAPF 2.5e-4f      // ambiguity band; pipeline error vs fp64-exact ~5e-5 tail -> >=5x margin
#define NS_D (8.0/255.0)
#define EPI_STRIDE 258    // floats per epilogue pos-row (256 ch + pad)
#define LIST_CAP 65536
#define XT_BYTES 33792    // one image's [66][2][128] bf16 tile

typedef __bf16 bf16x8 __attribute__((ext_vector_type(8)));
typedef float f32x4 __attribute__((ext_vector_type(4)));

__device__ __forceinline__ unsigned short bf_bits(float v) {
    __bf16 b = (__bf16)v;
    return __builtin_bit_cast(unsigned short, b);
}
__device__ __forceinline__ float bf_round(float v) { return (float)(__bf16)v; }

// swizzled byte offset into xT LDS tile: [ww 0..65][s 0..1][ci 0..127] bf16, row=512B
__device__ __forceinline__ int xoff(int ww, int s, int ci) {
    int byte = (ww << 9) + (s << 8) + (ci << 1);
    return byte ^ ((ww & 7) << 4);
}

// ---- 32-bit monotone float keys
__device__ __forceinline__ uint32_t skey32(float v) {
    uint32_t b = __float_as_uint(v);
    return (b & 0x80000000u) ? ~b : (b | 0x80000000u);
}
__device__ __forceinline__ float unskey32(uint32_t k) {
    uint32_t b = (k & 0x80000000u) ? (k & 0x7FFFFFFFu) : ~k;
    return __uint_as_float(b);
}

// ---- 64-bit keys (fixup kernel, exact fp64 path)
__device__ __forceinline__ uint64_t sortkey(double v) {
    uint64_t b = (uint64_t)__double_as_longlong(v);
    return (b & 0x8000000000000000ULL) ? ~b : (b | 0x8000000000000000ULL);
}
__device__ __forceinline__ double unsortkey(uint64_t k) {
    uint64_t b = (k & 0x8000000000000000ULL) ? (k & 0x7FFFFFFFFFFFFFFFULL) : ~k;
    return __longlong_as_double((long long)b);
}

// per-wave exact select over 256 u32 keys (4/lane): 64th/65th largest + exact count at prefix.
// bestcnt != 64  <=>  fp32 keys cannot uniquely separate rank 64/65 (ties) -> caller must flag.
__device__ __forceinline__ void select64_u32(const uint32_t u[4], uint32_t& k64, uint32_t& k65, int& bestcnt) {
    uint32_t prefix = 0;
    bestcnt = 256;
    for (int bit = 31; bit >= 0; --bit) {
        uint32_t cand = prefix | (1u << bit);
        int cnt = __popcll(__ballot(u[0] >= cand)) + __popcll(__ballot(u[1] >= cand))
                + __popcll(__ballot(u[2] >= cand)) + __popcll(__ballot(u[3] >= cand));
        if (cnt >= TOPK) {
            prefix = cand;
            bestcnt = cnt;
            if (cnt == TOPK) break;
        }
    }
    uint32_t mn = 0xFFFFFFFFu, mx = 0u;
#pragma unroll
    for (int j = 0; j < 4; ++j) {
        if (u[j] >= prefix) { if (u[j] < mn) mn = u[j]; }
        else                { if (u[j] > mx) mx = u[j]; }
    }
    for (int m = 1; m < 64; m <<= 1) {
        uint32_t a = (uint32_t)__shfl_xor((int)mn, m, 64);
        if (a < mn) mn = a;
        uint32_t b = (uint32_t)__shfl_xor((int)mx, m, 64);
        if (b > mx) mx = b;
    }
    k64 = mn; k65 = mx;
}

// per-wave exact select over 256 u64 keys (fixup path)
__device__ __forceinline__ void select64(const uint64_t u[4], uint64_t& k64, uint64_t& k65) {
    uint64_t prefix = 0;
    for (int bit = 63; bit >= 0; --bit) {
        uint64_t cand = prefix | (1ULL << bit);
        int cnt = __popcll(__ballot(u[0] >= cand)) + __popcll(__ballot(u[1] >= cand))
                + __popcll(__ballot(u[2] >= cand)) + __popcll(__ballot(u[3] >= cand));
        if (cnt >= TOPK) {
            prefix = cand;
            if (cnt == TOPK) break;
        }
    }
    uint64_t mn = ~0ULL, mx = 0ULL;
#pragma unroll
    for (int j = 0; j < 4; ++j) {
        if (u[j] >= prefix) { if (u[j] < mn) mn = u[j]; }
        else                { if (u[j] > mx) mx = u[j]; }
    }
    for (int m = 1; m < 64; m <<= 1) {
        uint64_t a = (uint64_t)__shfl_xor((unsigned long long)mn, m, 64);
        if (a < mn) mn = a;
        uint64_t b = (uint64_t)__shfl_xor((unsigned long long)mx, m, 64);
        if (b > mx) mx = b;
    }
    k64 = mn; k65 = mx;
}

// ---------------- prep (merged): absw (fp64) + wT (fp32, fixup) + wB (bf16 hi/lo) + counter reset
__global__ __launch_bounds__(128) void prep_all(const float* __restrict__ w,
                                                double* __restrict__ absw,
                                                float* __restrict__ wT,
                                                unsigned short* __restrict__ wB,
                                                int* __restrict__ counter) {
    const int c = blockIdx.x;      // 0..255
    const int ci = threadIdx.x;    // 0..127
    if (c == 0 && ci == 0) counter[0] = 0;
    double s = 0.0;
#pragma unroll
    for (int r = 0; r < 9; ++r) {
        float v = w[((size_t)c * CIN + ci) * 9 + r];
        s += fabs((double)v);
        float hf = bf_round(v);
        wT[((size_t)(r * CIN) + ci) * COUT + c] = v;
        wB[((size_t)r * COUT + c) * CIN + ci] = bf_bits(v);                 // split 0 (hi)
        wB[((size_t)(9 + r) * COUT + c) * CIN + ci] = bf_bits(v - hf);      // split 1 (lo)
    }
    __shared__ double red[2];
    for (int m = 32; m; m >>= 1) s += __shfl_xor(s, m, 64);
    if ((ci & 63) == 0) red[ci >> 6] = s;
    __syncthreads();
    if (ci == 0) absw[c] = red[0] + red[1];
}

// ---------------- fused: bf16-split MFMA conv + fp32 epilogue + ambiguity flagging
// (R5 structure: compiler-scheduled K-loop, 2 images/block, 2x32-position epilogue passes)
__global__ __launch_bounds__(256, 2) void fused_kernel(
    const float* __restrict__ x,
    const float* __restrict__ relu_bias,
    const float* __restrict__ noise,
    const double* __restrict__ absw,
    const unsigned short* __restrict__ wB,   // bf16 bits [s][kh][kw][c][ci]
    float* __restrict__ out,
    int* __restrict__ counter,
    int* __restrict__ list) {

    __shared__ alignas(16) union {
        unsigned short xT[2 * 66 * 256];   // 2 images x [ww][s][ci], swizzled; 67584 B
        float o[32 * EPI_STRIDE];          // 33024 B  (32 positions per pass)
    } U;
    __shared__ float lds_absw[COUT];
    __shared__ float lds_bias[COUT];
    __shared__ uint32_t thrk[32];

    const int tid = threadIdx.x;
    const int lane = tid & 63;
    const int wv = tid >> 6;          // channel quarter: c in [wv*64, wv*64+64)

    // XCD-aware bijective swizzle: 1024 blocks, 8 XCDs
    const int bid = ((int)(blockIdx.x & 7) << 7) + ((int)blockIdx.x >> 3);
    const int b0 = (bid >> 6) * 2;    // image pair
    const int h = bid & 63;

    lds_absw[tid] = (float)absw[tid];
    lds_bias[tid] = relu_bias[tid];

    const int kgrp8 = (lane >> 4) << 3;

    f32x4 acc[2][4][4];   // [img][m-tile 16pos][n-tile 16ch]
#pragma unroll
    for (int g = 0; g < 2; ++g)
#pragma unroll
        for (int i = 0; i < 4; ++i)
#pragma unroll
            for (int j = 0; j < 4; ++j) {
                acc[g][i][j][0] = 0.f; acc[g][i][j][1] = 0.f;
                acc[g][i][j][2] = 0.f; acc[g][i][j][3] = 0.f;
            }

    char* xb = (char*)U.xT;

    // halo columns ww=0 and ww=65 (zeros), both splits, both images
    if (tid < 128) {
        int img = tid >> 6;
        int t = tid & 63;
        int wwz = (t & 32) ? 65 : 0;
        int sz = (t >> 4) & 1;
        int c0z = (t & 15) << 3;
        bf16x8 z;
#pragma unroll
        for (int j = 0; j < 8; ++j) z[j] = (__bf16)0.f;
        *(bf16x8*)(xb + img * XT_BYTES + xoff(wwz, sz, c0z)) = z;
    }

    // B pointer lane offset: channel = wv*64 + (lane&15) (+16 per nt), k = (lane>>4)*8 within ci0 chunk
    const int laneB = ((lane & 15) << 7) + ((lane >> 4) << 3) + (wv << 13);

    for (int kh = 0; kh < 3; ++kh) {
        const int r = h + kh - 1;
        if (r < 0 || r >= HH) continue;   // uniform per block
        __syncthreads();                  // previous kh readers done (also covers halo init)
        // ---- stage both images' x row-slab -> xT (bf16 hi/lo, transposed, swizzled)
        {
            const int w = lane;           // ww = w+1
#pragma unroll
            for (int img = 0; img < 2; ++img) {
                const float* xr = x + (((size_t)(b0 + img) * CIN) * HH + (size_t)r) * WW;
                char* xbi = xb + img * XT_BYTES;
#pragma unroll
                for (int rep = 0; rep < 4; ++rep) {
                    const int c0 = rep * 32 + wv * 8;
                    const float* px = xr + (size_t)c0 * (HH * WW) + w;
                    bf16x8 hv, lv;
#pragma unroll
                    for (int j = 0; j < 8; ++j) {
                        float v = px[j * (HH * WW)];
                        float hf = bf_round(v);
                        hv[j] = (__bf16)v;
                        lv[j] = (__bf16)(v - hf);
                    }
                    *(bf16x8*)(xbi + xoff(w + 1, 0, c0)) = hv;
                    *(bf16x8*)(xbi + xoff(w + 1, 1, c0)) = lv;
                }
            }
        }
        __syncthreads();
        // ---- MFMA K-loop (compiler-scheduled; 3-kw window gives load-hoisting room)
#pragma unroll 1
        for (int ci0 = 0; ci0 < CIN; ci0 += 32) {
#pragma unroll
            for (int kw = 0; kw < 3; ++kw) {
                const unsigned short* wp0 = wB + (size_t)(kh * 3 + kw) * 32768 + ci0 + laneB;
                const unsigned short* wp1 = wp0 + (size_t)9 * 32768;
                bf16x8 bh[4], bl[4];
#pragma unroll
                for (int nt = 0; nt < 4; ++nt) {
                    bh[nt] = *(const bf16x8*)(wp0 + nt * 2048);
                    bl[nt] = *(const bf16x8*)(wp1 + nt * 2048);
                }
                bf16x8 ah[2][4], al[2][4];
#pragma unroll
                for (int img = 0; img < 2; ++img)
#pragma unroll
                    for (int mt = 0; mt < 4; ++mt) {
                        const int ww = (mt << 4) + (lane & 15) + kw;
                        ah[img][mt] = *(const bf16x8*)(xb + img * XT_BYTES + xoff(ww, 0, ci0 + kgrp8));
                        al[img][mt] = *(const bf16x8*)(xb + img * XT_BYTES + xoff(ww, 1, ci0 + kgrp8));
                    }
#pragma unroll
                for (int img = 0; img < 2; ++img)
#pragma unroll
                    for (int nt = 0; nt < 4; ++nt) {
#pragma unroll
                        for (int mt = 0; mt < 4; ++mt)
                            acc[img][mt][nt] = __builtin_amdgcn_mfma_f32_16x16x32_bf16(ah[img][mt], bh[nt], acc[img][mt][nt], 0, 0, 0);
#pragma unroll
                        for (int mt = 0; mt < 4; ++mt)
                            acc[img][mt][nt] = __builtin_amdgcn_mfma_f32_16x16x32_bf16(al[img][mt], bh[nt], acc[img][mt][nt], 0, 0, 0);
#pragma unroll
                        for (int mt = 0; mt < 4; ++mt)
                            acc[img][mt][nt] = __builtin_amdgcn_mfma_f32_16x16x32_bf16(ah[img][mt], bl[nt], acc[img][mt][nt], 0, 0, 0);
                    }
            }
        }
    }

    // ---------- epilogue: per image, two 32-position passes, all fp32
#pragma unroll
    for (int img = 0; img < 2; ++img) {
        const int b = b0 + img;
#pragma unroll
        for (int q = 0; q < 2; ++q) {
            __syncthreads();
            // phase 1: scatter acc (m-tiles 2q, 2q+1) -> U.o[pos_local][ch]
            // D-frag layout (m89-verified): ch = lane&15 (+tile), pos = (lane>>4)*4 + reg
            {
                const int pl0 = (lane >> 4) << 2;
                const int cb = (wv << 6) + (lane & 15);
#pragma unroll
                for (int half = 0; half < 2; ++half) {
                    const int mt = q * 2 + half;
#pragma unroll
                    for (int nt = 0; nt < 4; ++nt)
#pragma unroll
                        for (int rr = 0; rr < 4; ++rr)
                            U.o[(half * 16 + pl0 + rr) * EPI_STRIDE + cb + nt * 16] = acc[img][mt][nt][rr];
                }
            }
            __syncthreads();
            // phase 2: add noise (fp32)
            {
                int wl = tid & 31;
                int cg = tid >> 5;            // 0..7
                int wg = q * 32 + wl;
#pragma unroll 4
                for (int it = 0; it < 32; ++it) {
                    int c = cg + 8 * it;
                    float u = noise[((size_t)(b * COUT + c) * HH + h) * WW + wg];
                    U.o[wl * EPI_STRIDE + c] += lds_absw[c] * NS_F * (2.f * u - 1.f);
                }
            }
            __syncthreads();
            // phase 3: exact 64th/65th per position (u32 keys); flag ambiguous pixels
            {
#pragma unroll 1
                for (int pp = 0; pp < 8; ++pp) {
                    int pl = wv * 8 + pp;
                    uint32_t u[4];
#pragma unroll
                    for (int j = 0; j < 4; ++j)
                        u[j] = skey32(U.o[pl * EPI_STRIDE + lane + 64 * j]);
                    uint32_t k64, k65; int bcnt;
                    select64_u32(u, k64, k65, bcnt);
                    if (lane == 0) {
                        thrk[pl] = k64;
                        float t64 = unskey32(k64), t65 = unskey32(k65);
                        if (bcnt != 64 || t64 - t65 < GAPF) {
                            int idx = atomicAdd(counter, 1);
                            if (idx < LIST_CAP) list[idx] = (b << 12) | (h << 6) | (q * 32 + pl);
                        }
                    }
                }
            }
            __syncthreads();
            // phase 4: threshold in key space, +bias, relu, store
            {
                int wl = tid & 31;
                int cg = tid >> 5;
                int wg = q * 32 + wl;
                uint32_t tk = thrk[wl];
#pragma unroll 4
                for (int it = 0; it < 32; ++it) {
                    int c = cg + 8 * it;
                    float v = U.o[wl * EPI_STRIDE + c];
                    float o = (skey32(v) >= tk ? v : 0.f) + lds_bias[c];
                    out[((size_t)(b * COUT + c) * HH + h) * WW + wg] = fmaxf(o, 0.f);
                }
            }
        }
    }
}

// ---------------- fixup: exact fp64 recompute of flagged pixels, 4 per block (R6-proven)
__global__ __launch_bounds__(256, 2) void fixup_kernel(
    const float* __restrict__ x,
    const float* __restrict__ wT,       // [(kh*3+kw)*128+ci][c]
    const float* __restrict__ relu_bias,
    const float* __restrict__ noise,
    const double* __restrict__ absw,
    float* __restrict__ out,
    const int* __restrict__ counter,
    const int* __restrict__ list) {

    __shared__ double xs[4][CIN * 9];
    __shared__ uint64_t keys[4][COUT];

    int n = counter[0];
    if (n > LIST_CAP) n = LIST_CAP;

    for (int base = blockIdx.x * 4; base < n; base += gridDim.x * 4) {
        const int np = min(4, n - base);
        __syncthreads();
        for (int q = 0; q < np; ++q) {
            int pix = list[base + q];
            int bb = pix >> 12, hh = (pix >> 6) & 63, ww = pix & 63;
            for (int t = threadIdx.x; t < CIN * 9; t += 256) {
                int r = t >> 7, ci = t & 127;
                int kh = r / 3, kw = r % 3;
                int hr = hh + kh - 1, wr = ww + kw - 1;
                xs[q][t] = (hr >= 0 && hr < HH && wr >= 0 && wr < WW)
                    ? (double)x[(((size_t)(bb * CIN + ci) * HH + hr) * WW) + wr] : 0.0;
            }
        }
        __syncthreads();
        const int c = threadIdx.x;
        double s[4] = {0.0, 0.0, 0.0, 0.0};
        for (int row = 0; row < CIN * 9; ++row) {
            double wv = (double)wT[(size_t)row * COUT + c];
            s[0] = fma(wv, xs[0][row], s[0]);
            s[1] = fma(wv, xs[1][row], s[1]);
            s[2] = fma(wv, xs[2][row], s[2]);
            s[3] = fma(wv, xs[3][row], s[3]);
        }
#pragma unroll 1
        for (int q = 0; q < np; ++q) {
            int pix = list[base + q];
            int bb = pix >> 12, hh = (pix >> 6) & 63, ww = pix & 63;
            double u = (double)noise[(((size_t)(bb * COUT + c) * HH + hh) * WW) + ww];
            s[q] += absw[c] * NS_D * (2.0 * u - 1.0);
            keys[q][c] = sortkey(s[q]);
        }
        __syncthreads();
#pragma unroll 1
        for (int q = 0; q < np; ++q) {
            uint64_t uu[4];
            int lane = threadIdx.x & 63;
#pragma unroll
            for (int j = 0; j < 4; ++j) uu[j] = keys[q][lane + 64 * j];
            uint64_t k64, k65;
            select64(uu, k64, k65);
            double t64 = unsortkey(k64);
            int pix = list[base + q];
            int bb = pix >> 12, hh = (pix >> 6) & 63, ww = pix & 63;
            double o = (s[q] >= t64 ? s[q] : 0.0) + (double)relu_bias[c];
            out[(((size_t)(bb * COUT + c) * HH + hh) * WW) + ww] = (float)fmax(o, 0.0);
        }
    }
}

extern "C" void kernel_launch(void* const* d_in, const int* in_sizes, int n_in,
                              void* d_out, int out_size, void* d_ws, size_t ws_size,
                              hipStream_t stream) {
    const float* x         = (const float*)d_in[0];
    const float* weight    = (const float*)d_in[1];
    const float* relu_bias = (const float*)d_in[2];
    const float* noise_u   = (const float*)d_in[3];
    float* out = (float*)d_out;

    char* ws = (char*)d_ws;
    double* absw          = (double*)ws;                                   // 2 KB
    float*  wT            = (float*)(ws + 2048);                           // 1,179,648 B
    int*    cnt           = (int*)(ws + 2048 + 1179648);                   // 16 B slot
    int*    list          = (int*)(ws + 2048 + 1179648 + 16);              // 256 KB
    unsigned short* wBq   = (unsigned short*)(ws + 2048 + 1179648 + 16 + 262144); // 1,179,648 B

    prep_all<<<COUT, 128, 0, stream>>>(weight, absw, wT, wBq, cnt);
    fused_kernel<<<(BB / 2) * HH, 256, 0, stream>>>(x, relu_bias, noise_u, absw, wBq, out, cnt, list);
    fixup_kernel<<<1024, 256, 0, stream>>>(x, wT, relu_bias, noise_u, absw, out, cnt, list);
}

// Round 9
// 611.632 us; speedup vs baseline: 1.3175x; 1.0406x over previous
//
#include <hip/hip_runtime.h>
#include <stdint.h>

#define BB 32
#define CIN 128
#define COUT 256
#define HH 64
#define WW 64
#define TOPK 64
#define NS_F (8.0f/255.0f)
#define GAPF 2.5e-4f      // ambiguity band; pipeline error vs fp64-exact ~5e-5 tail -> >=5x margin
#define NS_D (8.0/255.0)
#define EPI_STRIDE 258    // floats per epilogue pos-row (256 ch + pad)
#define LIST_CAP 65536
#define XT_BYTES 33792    // one image's [66][2][128] bf16 tile

typedef __bf16 bf16x8 __attribute__((ext_vector_type(8)));
typedef float f32x4 __attribute__((ext_vector_type(4)));

__device__ __forceinline__ unsigned short bf_bits(float v) {
    __bf16 b = (__bf16)v;
    return __builtin_bit_cast(unsigned short, b);
}
__device__ __forceinline__ float bf_round(float v) { return (float)(__bf16)v; }

// swizzled byte offset into xT LDS tile: [ww 0..65][s 0..1][ci 0..127] bf16, row=512B
__device__ __forceinline__ int xoff(int ww, int s, int ci) {
    int byte = (ww << 9) + (s << 8) + (ci << 1);
    return byte ^ ((ww & 7) << 4);
}

// ---- 32-bit monotone float keys
__device__ __forceinline__ uint32_t skey32(float v) {
    uint32_t b = __float_as_uint(v);
    return (b & 0x80000000u) ? ~b : (b | 0x80000000u);
}
__device__ __forceinline__ float unskey32(uint32_t k) {
    uint32_t b = (k & 0x80000000u) ? (k & 0x7FFFFFFFu) : ~k;
    return __uint_as_float(b);
}

// ---- 64-bit keys (fixup kernel, exact fp64 path)
__device__ __forceinline__ uint64_t sortkey(double v) {
    uint64_t b = (uint64_t)__double_as_longlong(v);
    return (b & 0x8000000000000000ULL) ? ~b : (b | 0x8000000000000000ULL);
}
__device__ __forceinline__ double unsortkey(uint64_t k) {
    uint64_t b = (k & 0x8000000000000000ULL) ? (k & 0x7FFFFFFFFFFFFFFFULL) : ~k;
    return __longlong_as_double((long long)b);
}

// per-wave exact select over 256 u32 keys (4/lane): 64th/65th largest + exact count at prefix.
// bestcnt != 64  <=>  fp32 keys cannot uniquely separate rank 64/65 (ties) -> caller must flag.
__device__ __forceinline__ void select64_u32(const uint32_t u[4], uint32_t& k64, uint32_t& k65, int& bestcnt) {
    uint32_t prefix = 0;
    bestcnt = 256;
    for (int bit = 31; bit >= 0; --bit) {
        uint32_t cand = prefix | (1u << bit);
        int cnt = __popcll(__ballot(u[0] >= cand)) + __popcll(__ballot(u[1] >= cand))
                + __popcll(__ballot(u[2] >= cand)) + __popcll(__ballot(u[3] >= cand));
        if (cnt >= TOPK) {
            prefix = cand;
            bestcnt = cnt;
            if (cnt == TOPK) break;
        }
    }
    uint32_t mn = 0xFFFFFFFFu, mx = 0u;
#pragma unroll
    for (int j = 0; j < 4; ++j) {
        if (u[j] >= prefix) { if (u[j] < mn) mn = u[j]; }
        else                { if (u[j] > mx) mx = u[j]; }
    }
    for (int m = 1; m < 64; m <<= 1) {
        uint32_t a = (uint32_t)__shfl_xor((int)mn, m, 64);
        if (a < mn) mn = a;
        uint32_t b = (uint32_t)__shfl_xor((int)mx, m, 64);
        if (b > mx) mx = b;
    }
    k64 = mn; k65 = mx;
}

// per-wave exact select over 256 u64 keys (fixup path)
__device__ __forceinline__ void select64(const uint64_t u[4], uint64_t& k64, uint64_t& k65) {
    uint64_t prefix = 0;
    for (int bit = 63; bit >= 0; --bit) {
        uint64_t cand = prefix | (1ULL << bit);
        int cnt = __popcll(__ballot(u[0] >= cand)) + __popcll(__ballot(u[1] >= cand))
                + __popcll(__ballot(u[2] >= cand)) + __popcll(__ballot(u[3] >= cand));
        if (cnt >= TOPK) {
            prefix = cand;
            if (cnt == TOPK) break;
        }
    }
    uint64_t mn = ~0ULL, mx = 0ULL;
#pragma unroll
    for (int j = 0; j < 4; ++j) {
        if (u[j] >= prefix) { if (u[j] < mn) mn = u[j]; }
        else                { if (u[j] > mx) mx = u[j]; }
    }
    for (int m = 1; m < 64; m <<= 1) {
        uint64_t a = (uint64_t)__shfl_xor((unsigned long long)mn, m, 64);
        if (a < mn) mn = a;
        uint64_t b = (uint64_t)__shfl_xor((unsigned long long)mx, m, 64);
        if (b > mx) mx = b;
    }
    k64 = mn; k65 = mx;
}

// ---------------- prep (merged): absw (fp64) + wT (fp32, fixup) + wB (bf16 hi/lo) + counter reset
__global__ __launch_bounds__(128) void prep_all(const float* __restrict__ w,
                                                double* __restrict__ absw,
                                                float* __restrict__ wT,
                                                unsigned short* __restrict__ wB,
                                                int* __restrict__ counter) {
    const int c = blockIdx.x;      // 0..255
    const int ci = threadIdx.x;    // 0..127
    if (c == 0 && ci == 0) counter[0] = 0;
    double s = 0.0;
#pragma unroll
    for (int r = 0; r < 9; ++r) {
        float v = w[((size_t)c * CIN + ci) * 9 + r];
        s += fabs((double)v);
        float hf = bf_round(v);
        wT[((size_t)(r * CIN) + ci) * COUT + c] = v;
        wB[((size_t)r * COUT + c) * CIN + ci] = bf_bits(v);                 // split 0 (hi)
        wB[((size_t)(9 + r) * COUT + c) * CIN + ci] = bf_bits(v - hf);      // split 1 (lo)
    }
    __shared__ double red[2];
    for (int m = 32; m; m >>= 1) s += __shfl_xor(s, m, 64);
    if ((ci & 63) == 0) red[ci >> 6] = s;
    __syncthreads();
    if (ci == 0) absw[c] = red[0] + red[1];
}

// ---------------- fused: bf16-split MFMA conv + fp32 epilogue + ambiguity flagging
// (R5 structure: compiler-scheduled K-loop, 2 images/block, 2x32-position epilogue passes)
__global__ __launch_bounds__(256, 2) void fused_kernel(
    const float* __restrict__ x,
    const float* __restrict__ relu_bias,
    const float* __restrict__ noise,
    const double* __restrict__ absw,
    const unsigned short* __restrict__ wB,   // bf16 bits [s][kh][kw][c][ci]
    float* __restrict__ out,
    int* __restrict__ counter,
    int* __restrict__ list) {

    __shared__ alignas(16) union {
        unsigned short xT[2 * 66 * 256];   // 2 images x [ww][s][ci], swizzled; 67584 B
        float o[32 * EPI_STRIDE];          // 33024 B  (32 positions per pass)
    } U;
    __shared__ float lds_absw[COUT];
    __shared__ float lds_bias[COUT];
    __shared__ uint32_t thrk[32];

    const int tid = threadIdx.x;
    const int lane = tid & 63;
    const int wv = tid >> 6;          // channel quarter: c in [wv*64, wv*64+64)

    // XCD-aware bijective swizzle: 1024 blocks, 8 XCDs
    const int bid = ((int)(blockIdx.x & 7) << 7) + ((int)blockIdx.x >> 3);
    const int b0 = (bid >> 6) * 2;    // image pair
    const int h = bid & 63;

    lds_absw[tid] = (float)absw[tid];
    lds_bias[tid] = relu_bias[tid];

    const int kgrp8 = (lane >> 4) << 3;

    f32x4 acc[2][4][4];   // [img][m-tile 16pos][n-tile 16ch]
#pragma unroll
    for (int g = 0; g < 2; ++g)
#pragma unroll
        for (int i = 0; i < 4; ++i)
#pragma unroll
            for (int j = 0; j < 4; ++j) {
                acc[g][i][j][0] = 0.f; acc[g][i][j][1] = 0.f;
                acc[g][i][j][2] = 0.f; acc[g][i][j][3] = 0.f;
            }

    char* xb = (char*)U.xT;

    // halo columns ww=0 and ww=65 (zeros), both splits, both images
    if (tid < 128) {
        int img = tid >> 6;
        int t = tid & 63;
        int wwz = (t & 32) ? 65 : 0;
        int sz = (t >> 4) & 1;
        int c0z = (t & 15) << 3;
        bf16x8 z;
#pragma unroll
        for (int j = 0; j < 8; ++j) z[j] = (__bf16)0.f;
        *(bf16x8*)(xb + img * XT_BYTES + xoff(wwz, sz, c0z)) = z;
    }

    // B pointer lane offset: channel = wv*64 + (lane&15) (+16 per nt), k = (lane>>4)*8 within ci0 chunk
    const int laneB = ((lane & 15) << 7) + ((lane >> 4) << 3) + (wv << 13);

    for (int kh = 0; kh < 3; ++kh) {
        const int r = h + kh - 1;
        if (r < 0 || r >= HH) continue;   // uniform per block
        __syncthreads();                  // previous kh readers done (also covers halo init)
        // ---- stage both images' x row-slab -> xT (bf16 hi/lo, transposed, swizzled)
        {
            const int w = lane;           // ww = w+1
#pragma unroll
            for (int img = 0; img < 2; ++img) {
                const float* xr = x + (((size_t)(b0 + img) * CIN) * HH + (size_t)r) * WW;
                char* xbi = xb + img * XT_BYTES;
#pragma unroll
                for (int rep = 0; rep < 4; ++rep) {
                    const int c0 = rep * 32 + wv * 8;
                    const float* px = xr + (size_t)c0 * (HH * WW) + w;
                    bf16x8 hv, lv;
#pragma unroll
                    for (int j = 0; j < 8; ++j) {
                        float v = px[j * (HH * WW)];
                        float hf = bf_round(v);
                        hv[j] = (__bf16)v;
                        lv[j] = (__bf16)(v - hf);
                    }
                    *(bf16x8*)(xbi + xoff(w + 1, 0, c0)) = hv;
                    *(bf16x8*)(xbi + xoff(w + 1, 1, c0)) = lv;
                }
            }
        }
        __syncthreads();
        // ---- MFMA K-loop (compiler-scheduled; 3-kw window gives load-hoisting room)
#pragma unroll 1
        for (int ci0 = 0; ci0 < CIN; ci0 += 32) {
#pragma unroll
            for (int kw = 0; kw < 3; ++kw) {
                const unsigned short* wp0 = wB + (size_t)(kh * 3 + kw) * 32768 + ci0 + laneB;
                const unsigned short* wp1 = wp0 + (size_t)9 * 32768;
                bf16x8 bh[4], bl[4];
#pragma unroll
                for (int nt = 0; nt < 4; ++nt) {
                    bh[nt] = *(const bf16x8*)(wp0 + nt * 2048);
                    bl[nt] = *(const bf16x8*)(wp1 + nt * 2048);
                }
                bf16x8 ah[2][4], al[2][4];
#pragma unroll
                for (int img = 0; img < 2; ++img)
#pragma unroll
                    for (int mt = 0; mt < 4; ++mt) {
                        const int ww = (mt << 4) + (lane & 15) + kw;
                        ah[img][mt] = *(const bf16x8*)(xb + img * XT_BYTES + xoff(ww, 0, ci0 + kgrp8));
                        al[img][mt] = *(const bf16x8*)(xb + img * XT_BYTES + xoff(ww, 1, ci0 + kgrp8));
                    }
#pragma unroll
                for (int img = 0; img < 2; ++img)
#pragma unroll
                    for (int nt = 0; nt < 4; ++nt) {
#pragma unroll
                        for (int mt = 0; mt < 4; ++mt)
                            acc[img][mt][nt] = __builtin_amdgcn_mfma_f32_16x16x32_bf16(ah[img][mt], bh[nt], acc[img][mt][nt], 0, 0, 0);
#pragma unroll
                        for (int mt = 0; mt < 4; ++mt)
                            acc[img][mt][nt] = __builtin_amdgcn_mfma_f32_16x16x32_bf16(al[img][mt], bh[nt], acc[img][mt][nt], 0, 0, 0);
#pragma unroll
                        for (int mt = 0; mt < 4; ++mt)
                            acc[img][mt][nt] = __builtin_amdgcn_mfma_f32_16x16x32_bf16(ah[img][mt], bl[nt], acc[img][mt][nt], 0, 0, 0);
                    }
            }
        }
    }

    // ---------- epilogue: per image, two 32-position passes, all fp32
#pragma unroll
    for (int img = 0; img < 2; ++img) {
        const int b = b0 + img;
#pragma unroll
        for (int q = 0; q < 2; ++q) {
            __syncthreads();
            // phase 1: scatter acc (m-tiles 2q, 2q+1) -> U.o[pos_local][ch]
            // D-frag layout (m89-verified): ch = lane&15 (+tile), pos = (lane>>4)*4 + reg
            {
                const int pl0 = (lane >> 4) << 2;
                const int cb = (wv << 6) + (lane & 15);
#pragma unroll
                for (int half = 0; half < 2; ++half) {
                    const int mt = q * 2 + half;
#pragma unroll
                    for (int nt = 0; nt < 4; ++nt)
#pragma unroll
                        for (int rr = 0; rr < 4; ++rr)
                            U.o[(half * 16 + pl0 + rr) * EPI_STRIDE + cb + nt * 16] = acc[img][mt][nt][rr];
                }
            }
            __syncthreads();
            // phase 2: add noise (fp32)
            {
                int wl = tid & 31;
                int cg = tid >> 5;            // 0..7
                int wg = q * 32 + wl;
#pragma unroll 4
                for (int it = 0; it < 32; ++it) {
                    int c = cg + 8 * it;
                    float u = noise[((size_t)(b * COUT + c) * HH + h) * WW + wg];
                    U.o[wl * EPI_STRIDE + c] += lds_absw[c] * NS_F * (2.f * u - 1.f);
                }
            }
            __syncthreads();
            // phase 3: exact 64th/65th per position (u32 keys); flag ambiguous pixels
            {
#pragma unroll 1
                for (int pp = 0; pp < 8; ++pp) {
                    int pl = wv * 8 + pp;
                    uint32_t u[4];
#pragma unroll
                    for (int j = 0; j < 4; ++j)
                        u[j] = skey32(U.o[pl * EPI_STRIDE + lane + 64 * j]);
                    uint32_t k64, k65; int bcnt;
                    select64_u32(u, k64, k65, bcnt);
                    if (lane == 0) {
                        thrk[pl] = k64;
                        float t64 = unskey32(k64), t65 = unskey32(k65);
                        if (bcnt != 64 || t64 - t65 < GAPF) {
                            int idx = atomicAdd(counter, 1);
                            if (idx < LIST_CAP) list[idx] = (b << 12) | (h << 6) | (q * 32 + pl);
                        }
                    }
                }
            }
            __syncthreads();
            // phase 4: threshold in key space, +bias, relu, store
            {
                int wl = tid & 31;
                int cg = tid >> 5;
                int wg = q * 32 + wl;
                uint32_t tk = thrk[wl];
#pragma unroll 4
                for (int it = 0; it < 32; ++it) {
                    int c = cg + 8 * it;
                    float v = U.o[wl * EPI_STRIDE + c];
                    float o = (skey32(v) >= tk ? v : 0.f) + lds_bias[c];
                    out[((size_t)(b * COUT + c) * HH + h) * WW + wg] = fmaxf(o, 0.f);
                }
            }
        }
    }
}

// ---------------- fixup: exact fp64 recompute of flagged pixels, 4 per block
// Main loop: 16-row register ping-pong (8 loads in flight while 32 fp64 FMAs retire)
__global__ __launch_bounds__(256, 2) void fixup_kernel(
    const float* __restrict__ x,
    const float* __restrict__ wT,       // [(kh*3+kw)*128+ci][c]
    const float* __restrict__ relu_bias,
    const float* __restrict__ noise,
    const double* __restrict__ absw,
    float* __restrict__ out,
    const int* __restrict__ counter,
    const int* __restrict__ list) {

    __shared__ double xs[4][CIN * 9];
    __shared__ uint64_t keys[4][COUT];

    int n = counter[0];
    if (n > LIST_CAP) n = LIST_CAP;

    for (int base = blockIdx.x * 4; base < n; base += gridDim.x * 4) {
        const int np = min(4, n - base);
        __syncthreads();
        for (int q = 0; q < np; ++q) {
            int pix = list[base + q];
            int bb = pix >> 12, hh = (pix >> 6) & 63, ww = pix & 63;
            for (int t = threadIdx.x; t < CIN * 9; t += 256) {
                int r = t >> 7, ci = t & 127;
                int kh = r / 3, kw = r % 3;
                int hr = hh + kh - 1, wr = ww + kw - 1;
                xs[q][t] = (hr >= 0 && hr < HH && wr >= 0 && wr < WW)
                    ? (double)x[(((size_t)(bb * CIN + ci) * HH + hr) * WW) + wr] : 0.0;
            }
        }
        __syncthreads();
        const int c = threadIdx.x;
        double s[4] = {0.0, 0.0, 0.0, 0.0};
        {
            const float* wp = wT + c;
            float wA[8], wBr[8];
#pragma unroll
            for (int k = 0; k < 8; ++k) wA[k] = wp[(size_t)k * COUT];
#pragma unroll 1
            for (int row = 0; row < CIN * 9; row += 16) {
                // issue loads for rows row+8..row+15 (independent of wA FMAs)
#pragma unroll
                for (int k = 0; k < 8; ++k) wBr[k] = wp[(size_t)(row + 8 + k) * COUT];
                // consume wA (rows row..row+7)
#pragma unroll
                for (int k = 0; k < 8; ++k) {
                    double wv = (double)wA[k];
                    s[0] = fma(wv, xs[0][row + k], s[0]);
                    s[1] = fma(wv, xs[1][row + k], s[1]);
                    s[2] = fma(wv, xs[2][row + k], s[2]);
                    s[3] = fma(wv, xs[3][row + k], s[3]);
                }
                // issue loads for rows row+16..row+23 (next iteration's wA)
                if (row + 16 < CIN * 9) {
#pragma unroll
                    for (int k = 0; k < 8; ++k) wA[k] = wp[(size_t)(row + 16 + k) * COUT];
                }
                // consume wBr (rows row+8..row+15)
#pragma unroll
                for (int k = 0; k < 8; ++k) {
                    double wv = (double)wBr[k];
                    s[0] = fma(wv, xs[0][row + 8 + k], s[0]);
                    s[1] = fma(wv, xs[1][row + 8 + k], s[1]);
                    s[2] = fma(wv, xs[2][row + 8 + k], s[2]);
                    s[3] = fma(wv, xs[3][row + 8 + k], s[3]);
                }
            }
        }
#pragma unroll 1
        for (int q = 0; q < np; ++q) {
            int pix = list[base + q];
            int bb = pix >> 12, hh = (pix >> 6) & 63, ww = pix & 63;
            double u = (double)noise[(((size_t)(bb * COUT + c) * HH + hh) * WW) + ww];
            s[q] += absw[c] * NS_D * (2.0 * u - 1.0);
            keys[q][c] = sortkey(s[q]);
        }
        __syncthreads();
#pragma unroll 1
        for (int q = 0; q < np; ++q) {
            uint64_t uu[4];
            int lane = threadIdx.x & 63;
#pragma unroll
            for (int j = 0; j < 4; ++j) uu[j] = keys[q][lane + 64 * j];
            uint64_t k64, k65;
            select64(uu, k64, k65);
            double t64 = unsortkey(k64);
            int pix = list[base + q];
            int bb = pix >> 12, hh = (pix >> 6) & 63, ww = pix & 63;
            double o = (s[q] >= t64 ? s[q] : 0.0) + (double)relu_bias[c];
            out[(((size_t)(bb * COUT + c) * HH + hh) * WW) + ww] = (float)fmax(o, 0.0);
        }
    }
}

extern "C" void kernel_launch(void* const* d_in, const int* in_sizes, int n_in,
                              void* d_out, int out_size, void* d_ws, size_t ws_size,
                              hipStream_t stream) {
    const float* x         = (const float*)d_in[0];
    const float* weight    = (const float*)d_in[1];
    const float* relu_bias = (const float*)d_in[2];
    const float* noise_u   = (const float*)d_in[3];
    float* out = (float*)d_out;

    char* ws = (char*)d_ws;
    double* absw          = (double*)ws;                                   // 2 KB
    float*  wT            = (float*)(ws + 2048);                           // 1,179,648 B
    int*    cnt           = (int*)(ws + 2048 + 1179648);                   // 16 B slot
    int*    list          = (int*)(ws + 2048 + 1179648 + 16);              // 256 KB
    unsigned short* wBq   = (unsigned short*)(ws + 2048 + 1179648 + 16 + 262144); // 1,179,648 B

    prep_all<<<COUT, 128, 0, stream>>>(weight, absw, wT, wBq, cnt);
    fused_kernel<<<(BB / 2) * HH, 256, 0, stream>>>(x, relu_bias, noise_u, absw, wBq, out, cnt, list);
    fixup_kernel<<<1024, 256, 0, stream>>>(x, wT, relu_bias, noise_u, absw, out, cnt, list);
}